// Round 5
// baseline (368.716 us; speedup 1.0000x reference)
//
#include <hip/hip_runtime.h>
#include <math.h>

// MultiLocalCosineLinear: B=65536 rows, D=768, C=100, P=4950 pairs.
// out layout (all float32): [0..B)  = preds (class id as float)
//                           [B..3B) = logits, row-major (B,2)
//
// R4: single fused kernel, 4 lanes per row, 16 rows per wave.
// R0-R3 were all stall-bound (~31% HBM, 36% VALU) on one-wave-per-row
// structure: deep butterfly reductions + few loads in flight. Now each
// 4-lane group owns a row end-to-end: top-2 scan, pair decode, dots+norms,
// epilogue. Reduction = 2 quad-perm shuffle steps; 16 independent rows per
// wave give ~48 outstanding float4 loads; no LDS/atomics/extra kernels.

#define D_DIM 768
#define C_DIM 100
#define EPS_N 1e-12

typedef float vf4 __attribute__((ext_vector_type(4)));

__device__ __forceinline__ bool vi_gt(float v0, int i0, float v1, int i1) {
    // lexicographic (value desc, index asc) — matches jax.lax.top_k + stable sort
    return (v0 > v1) || (v0 == v1 && i0 < i1);
}

__device__ __forceinline__ void t2up(float val, int idx,
                                     float& v1, int& i1, float& v2, int& i2) {
    if (vi_gt(val, idx, v1, i1)) { v2 = v1; i2 = i1; v1 = val; i1 = idx; }
    else if (vi_gt(val, idx, v2, i2)) { v2 = val; i2 = idx; }
}

__global__ __launch_bounds__(256) void fused_kernel(
    const float* __restrict__ x,
    const float* __restrict__ first_out,
    const float* __restrict__ weights,
    const float* __restrict__ sigma,
    float* __restrict__ out,
    int B)
{
    const int tid = blockIdx.x * 256 + threadIdx.x;
    const int gl  = tid & 3;          // lane within 4-lane group
    const int r   = tid >> 2;         // row this group owns
    if (r >= B) return;

    // ---------- phase 1: top-2 of first_out[r, 0:100] ----------
    // 25 float4s; trip t: group lanes read f4 idx {4t..4t+3} (contiguous 64B)
    const vf4* fov = (const vf4*)(first_out + (size_t)r * C_DIM);
    float v1 = -INFINITY, v2 = -INFINITY;
    int   i1 = 0x7fffffff, i2 = 0x7fffffff;
    #pragma unroll
    for (int t = 0; t < 7; ++t) {
        const int f4i = 4 * t + gl;
        if (f4i < 25) {
            vf4 e = fov[f4i];
            const int e0 = 4 * f4i;
            t2up(e.x, e0,     v1, i1, v2, i2);
            t2up(e.y, e0 + 1, v1, i1, v2, i2);
            t2up(e.z, e0 + 2, v1, i1, v2, i2);
            t2up(e.w, e0 + 3, v1, i1, v2, i2);
        }
    }
    // merge across the 4-lane group (xor 1, 2 stay within aligned quad)
    #pragma unroll
    for (int m = 1; m < 4; m <<= 1) {
        float ov1 = __shfl_xor(v1, m, 64);
        int   oi1 = __shfl_xor(i1, m, 64);
        float ov2 = __shfl_xor(v2, m, 64);
        int   oi2 = __shfl_xor(i2, m, 64);
        if (vi_gt(ov1, oi1, v1, i1)) {
            float nv2; int ni2;
            if (vi_gt(v1, i1, ov2, oi2)) { nv2 = v1;  ni2 = i1; }
            else                         { nv2 = ov2; ni2 = oi2; }
            v1 = ov1; i1 = oi1; v2 = nv2; i2 = ni2;
        } else {
            if (vi_gt(ov1, oi1, v2, i2)) { v2 = ov1; i2 = oi1; }
        }
    }
    // all 4 lanes of the group now agree
    const int a = min(i1, i2);
    const int b = max(i1, i2);
    const int p = b * (b - 1) / 2 + a;

    // ---------- phase 2: dots + norms over D=768 ----------
    // 192 f4 per row; trip tt: group reads f4 idx {4tt..4tt+3} of x, w0, w1
    const vf4* xv = (const vf4*)(x + (size_t)r * D_DIM);
    const vf4* wv = (const vf4*)(weights + (size_t)p * (2 * D_DIM));

    float  xx = 0.f;                       // common positive scale — f32 ok
    double d0 = 0.0, d1 = 0.0, n0 = 0.0, n1 = 0.0;   // feed argmax — f64
    #pragma unroll 4
    for (int tt = 0; tt < 48; ++tt) {
        const int f4i = 4 * tt + gl;
        vf4 xa = xv[f4i];
        vf4 w0 = wv[f4i];
        vf4 w1 = wv[192 + f4i];
        xx += xa.x * xa.x + xa.y * xa.y + xa.z * xa.z + xa.w * xa.w;
        d0 += (double)xa.x * w0.x + (double)xa.y * w0.y
            + (double)xa.z * w0.z + (double)xa.w * w0.w;
        d1 += (double)xa.x * w1.x + (double)xa.y * w1.y
            + (double)xa.z * w1.z + (double)xa.w * w1.w;
        n0 += (double)w0.x * w0.x + (double)w0.y * w0.y
            + (double)w0.z * w0.z + (double)w0.w * w0.w;
        n1 += (double)w1.x * w1.x + (double)w1.y * w1.y
            + (double)w1.z * w1.z + (double)w1.w * w1.w;
    }
    #pragma unroll
    for (int m = 1; m < 4; m <<= 1) {
        xx += __shfl_xor(xx, m, 64);
        d0 += __shfl_xor(d0, m, 64);
        d1 += __shfl_xor(d1, m, 64);
        n0 += __shfl_xor(n0, m, 64);
        n1 += __shfl_xor(n1, m, 64);
    }

    // ---------- epilogue: group-lane 0 ----------
    if (gl == 0) {
        const double s   = (double)sigma[p];
        const double inx = s / fmax(sqrt((double)xx), EPS_N);
        const double l0  = inx * d0 / fmax(sqrt(n0), EPS_N);
        const double l1  = inx * d1 / fmax(sqrt(n1), EPS_N);
        const int sel = (l1 > l0) ? 1 : 0;    // jnp.argmax: first index wins ties
        out[r] = (float)(sel ? b : a);
        float2 lg = make_float2((float)l0, (float)l1);
        *(float2*)(out + B + 2 * (size_t)r) = lg;   // 8B-aligned: B even
    }
}

extern "C" void kernel_launch(void* const* d_in, const int* in_sizes, int n_in,
                              void* d_out, int out_size, void* d_ws, size_t ws_size,
                              hipStream_t stream) {
    const float* x         = (const float*)d_in[0];
    const float* first_out = (const float*)d_in[1];
    const float* weights   = (const float*)d_in[2];
    const float* sigma     = (const float*)d_in[3];
    float* out = (float*)d_out;

    const int B = in_sizes[0] / D_DIM;     // 65536
    const int threads = B * 4;             // 4 lanes per row
    hipLaunchKernelGGL(fused_kernel, dim3((threads + 255) / 256), dim3(256),
                       0, stream, x, first_out, weights, sigma, out, B);
}

// Round 6
// 351.278 us; speedup vs baseline: 1.0496x; 1.0496x over previous
//
#include <hip/hip_runtime.h>
#include <math.h>

// MultiLocalCosineLinear: B=65536 rows, D=768, C=100, P=4950 pairs.
// out layout (all float32): [0..B)  = preds (class id as float)
//                           [B..3B) = logits, row-major (B,2)
//
// R5: pair-sorted row processing for L2 weight locality.
// Demand-BW model: per-row-gather designs (R0-R4) pay 393 MB of weight
// demand through L3 (~5 TB/s observed ceiling -> ~120 us floor). Fix:
// counting-sort rows by pair, hot kernel = one wave per sorted position
// (balanced), XCD-swizzled so each XCD owns a contiguous slice -> ~13
// consecutive waves share one 6 KB weight pair -> weights served by L2.
// K0 folds sigma/||w|| precompute + zeroes counts (no memset launch).

#define D_DIM 768
#define C_DIM 100
#define P_DIM 4950               // C*(C-1)/2
#define EPS_N 1e-12

typedef float vf4 __attribute__((ext_vector_type(4)));

__device__ __forceinline__ bool vi_gt(float v0, int i0, float v1, int i1) {
    // lexicographic (value desc, index asc) — matches jax.lax.top_k + stable sort
    return (v0 > v1) || (v0 == v1 && i0 < i1);
}

// ---------- K0: cbuf[row] = sigma[row/2] / max(||W_row||, eps); zero counts ----------
// one wave per weight vector (2P = 9900); also zeroes counts+cursors (2P ints)
__global__ __launch_bounds__(256) void prep_kernel(
    const float* __restrict__ weights,
    const float* __restrict__ sigma,
    double* __restrict__ cbuf,
    int* __restrict__ zero_ints,     // counts+cursors region
    int nrows, int nzero)
{
    const int gid = blockIdx.x * 256 + threadIdx.x;
    if (gid < nzero) zero_ints[gid] = 0;

    const int lane = threadIdx.x & 63;
    const int row = (blockIdx.x << 2) + (threadIdx.x >> 6);
    if (row >= nrows) return;

    const vf4* wv = (const vf4*)(weights + (size_t)row * D_DIM);
    double n = 0.0;
    #pragma unroll
    for (int j = 0; j < 3; ++j) {
        vf4 w = wv[lane + j * 64];
        n += (double)w.x * w.x + (double)w.y * w.y
           + (double)w.z * w.z + (double)w.w * w.w;
    }
    #pragma unroll
    for (int m = 1; m < 64; m <<= 1) n += __shfl_xor(n, m, 64);
    if (lane == 0)
        cbuf[row] = (double)sigma[row >> 1] / fmax(sqrt(n), EPS_N);
}

// ---------- K1: top-2 per row -> pairbuf[r], histogram counts[p] ----------
__global__ __launch_bounds__(256) void top2_kernel(
    const float* __restrict__ first_out,
    int* __restrict__ pairbuf,
    int* __restrict__ counts,
    int B)
{
    const int lane = threadIdx.x & 63;
    const int r = (blockIdx.x << 2) + (threadIdx.x >> 6);
    if (r >= B) return;

    const float* fo = first_out + (size_t)r * C_DIM;
    float e0 = fo[lane];
    int   j1 = lane + 64;
    float e1 = (j1 < C_DIM) ? fo[j1] : -INFINITY;

    float v1, v2; int i1, i2;
    if (vi_gt(e1, j1, e0, lane)) { v1 = e1; i1 = j1;   v2 = e0; i2 = lane; }
    else                         { v1 = e0; i1 = lane; v2 = e1; i2 = j1; }

    #pragma unroll
    for (int m = 1; m < 64; m <<= 1) {
        float ov1 = __shfl_xor(v1, m, 64);
        int   oi1 = __shfl_xor(i1, m, 64);
        float ov2 = __shfl_xor(v2, m, 64);
        int   oi2 = __shfl_xor(i2, m, 64);
        if (vi_gt(ov1, oi1, v1, i1)) {
            float nv2; int ni2;
            if (vi_gt(v1, i1, ov2, oi2)) { nv2 = v1;  ni2 = i1; }
            else                         { nv2 = ov2; ni2 = oi2; }
            v1 = ov1; i1 = oi1; v2 = nv2; i2 = ni2;
        } else {
            if (vi_gt(ov1, oi1, v2, i2)) { v2 = ov1; i2 = oi1; }
        }
    }
    if (lane == 0) {
        const int a = min(i1, i2);
        const int b = max(i1, i2);
        const int p = b * (b - 1) / 2 + a;
        pairbuf[r] = p;
        atomicAdd(&counts[p], 1);
    }
}

// ---------- K2: exclusive scan of counts[P] -> offsets[P] (single block) ----------
#define SCAN_T 256
#define CHUNK ((P_DIM + SCAN_T - 1) / SCAN_T)   // 20
__global__ __launch_bounds__(SCAN_T) void scan_kernel(
    const int* __restrict__ counts,
    int* __restrict__ offsets)
{
    __shared__ int sh[SCAN_T];
    const int t = threadIdx.x;
    int vals[CHUNK];
    int tot = 0;
    #pragma unroll
    for (int j = 0; j < CHUNK; ++j) {
        const int idx = t * CHUNK + j;
        const int v = (idx < P_DIM) ? counts[idx] : 0;
        vals[j] = v; tot += v;
    }
    sh[t] = tot;
    __syncthreads();
    for (int d = 1; d < SCAN_T; d <<= 1) {
        const int v = (t >= d) ? sh[t - d] : 0;
        __syncthreads();
        sh[t] += v;
        __syncthreads();
    }
    int run = (t == 0) ? 0 : sh[t - 1];
    #pragma unroll
    for (int j = 0; j < CHUNK; ++j) {
        const int idx = t * CHUNK + j;
        if (idx < P_DIM) offsets[idx] = run;
        run += vals[j];
    }
}

// ---------- K3: scatter packed (p<<16 | r) into pair-sorted rowlist ----------
__global__ __launch_bounds__(256) void scatter_kernel(
    const int* __restrict__ pairbuf,
    const int* __restrict__ offsets,
    int* __restrict__ cursors,
    int* __restrict__ rowlist,
    int B)
{
    const int r = blockIdx.x * 256 + threadIdx.x;
    if (r >= B) return;
    const int p = pairbuf[r];
    const int pos = offsets[p] + atomicAdd(&cursors[p], 1);
    rowlist[pos] = (p << 16) | (r & 0xFFFF);    // valid: B <= 65536, P < 8192
}

// ---------- K4: hot — one wave per sorted position, XCD-swizzled ----------
__global__ __launch_bounds__(256) void main_kernel(
    const float* __restrict__ x,
    const float* __restrict__ weights,
    const double* __restrict__ cbuf,
    const int* __restrict__ rowlist,
    float* __restrict__ out,
    int B, int blocks_per_xcd)
{
    const int lane = threadIdx.x & 63;
    // XCD swizzle: each XCD gets a contiguous slice of the pair-sorted list
    const int bid = blockIdx.x;
    const int logical = (bid & 7) * blocks_per_xcd + (bid >> 3);
    const int w = (logical << 2) + (threadIdx.x >> 6);
    if (w >= B) return;

    const int packed = __builtin_amdgcn_readfirstlane(rowlist[w]);
    const int r = packed & 0xFFFF;
    const int p = packed >> 16;

    const vf4* xv = (const vf4*)(x + (size_t)r * D_DIM);
    const vf4* wv = (const vf4*)(weights + (size_t)p * (2 * D_DIM));

    float  xx = 0.f;                 // common positive scale — f32 ok
    double d0 = 0.0, d1 = 0.0;       // feed argmax — f64
    #pragma unroll
    for (int j = 0; j < 3; ++j) {
        const int idx = lane + j * 64;
        vf4 xa = xv[idx];
        vf4 w0 = wv[idx];
        vf4 w1 = wv[192 + idx];
        xx += xa.x * xa.x + xa.y * xa.y + xa.z * xa.z + xa.w * xa.w;
        d0 += (double)xa.x * w0.x + (double)xa.y * w0.y
            + (double)xa.z * w0.z + (double)xa.w * w0.w;
        d1 += (double)xa.x * w1.x + (double)xa.y * w1.y
            + (double)xa.z * w1.z + (double)xa.w * w1.w;
    }
    #pragma unroll
    for (int m = 1; m < 64; m <<= 1) {
        xx += __shfl_xor(xx, m, 64);
        d0 += __shfl_xor(d0, m, 64);
        d1 += __shfl_xor(d1, m, 64);
    }

    if (lane == 0) {
        // decode (a,b) from p
        int b = (int)floor((sqrt(8.0 * (double)p + 1.0) + 1.0) * 0.5);
        if (b * (b - 1) / 2 > p) --b;
        if ((b + 1) * b / 2 <= p) ++b;
        const int a = p - b * (b - 1) / 2;

        const double inx = 1.0 / fmax(sqrt((double)xx), EPS_N);
        const double l0  = cbuf[2 * p]     * d0 * inx;
        const double l1  = cbuf[2 * p + 1] * d1 * inx;
        const int sel = (l1 > l0) ? 1 : 0;   // jnp.argmax: first index wins ties
        out[r] = (float)(sel ? b : a);
        float2 lg = make_float2((float)l0, (float)l1);
        *(float2*)(out + B + 2 * (size_t)r) = lg;
    }
}

extern "C" void kernel_launch(void* const* d_in, const int* in_sizes, int n_in,
                              void* d_out, int out_size, void* d_ws, size_t ws_size,
                              hipStream_t stream) {
    const float* x         = (const float*)d_in[0];
    const float* first_out = (const float*)d_in[1];
    const float* weights   = (const float*)d_in[2];
    const float* sigma     = (const float*)d_in[3];
    float* out = (float*)d_out;

    const int B  = in_sizes[0] / D_DIM;   // 65536
    const int P  = in_sizes[3];           // 4950
    const int NW = 2 * P;                 // 9900 weight vectors

    // ws layout: [cbuf 2P doubles][counts P][cursors P][offsets P][pairbuf B][rowlist B]
    double* cbuf = (double*)d_ws;
    int* counts  = (int*)(cbuf + NW);
    int* cursors = counts + P;
    int* offsets = cursors + P;
    int* pairbuf = offsets + P;
    int* rowlist = pairbuf + B;

    hipLaunchKernelGGL(prep_kernel, dim3((NW + 3) / 4), dim3(256), 0, stream,
                       weights, sigma, cbuf, counts, NW, 2 * P);
    hipLaunchKernelGGL(top2_kernel, dim3((B + 3) / 4), dim3(256), 0, stream,
                       first_out, pairbuf, counts, B);
    hipLaunchKernelGGL(scan_kernel, dim3(1), dim3(SCAN_T), 0, stream,
                       counts, offsets);
    hipLaunchKernelGGL(scatter_kernel, dim3((B + 255) / 256), dim3(256), 0, stream,
                       pairbuf, offsets, cursors, rowlist, B);

    const int nblocks = (B + 3) / 4;               // one wave per row
    const int bpx = (nblocks + 7) / 8;             // blocks per XCD slice
    hipLaunchKernelGGL(main_kernel, dim3(nblocks), dim3(256), 0, stream,
                       x, weights, cbuf, rowlist, out, B, bpx);
}

// Round 7
// 319.361 us; speedup vs baseline: 1.1545x; 1.0999x over previous
//
#include <hip/hip_runtime.h>
#include <math.h>

// MultiLocalCosineLinear: B=65536 rows, D=768, C=100, P=4950 pairs.
// out layout (all float32): [0..B)  = preds (class id as float)
//                           [B..3B) = logits, row-major (B,2)
//
// R6: R0 structure (single kernel, one wave per row — best measured config,
// 121 us) with ALL cross-lane traffic moved from the DS pipe (ds_swizzle via
// __shfl_xor) to DPP (row_shr + row_bcast scans, VALU speed, zero LDS-pipe).
// Theory: R0-R5's ~120 us floor = DS-pipe throughput+latency from ~54
// wave-wide swizzles per row. Reductions end in lane 63; epilogue on lane 63.

#define D_DIM 768
#define C_DIM 100
#define EPS_N 1e-12

typedef float vf4 __attribute__((ext_vector_type(4)));

// ---- DPP plumbing (all control args compile-time) ----
#define ROW_SHR1    0x111
#define ROW_SHR2    0x112
#define ROW_SHR4    0x114
#define ROW_SHR8    0x118
#define ROW_BCAST15 0x142
#define ROW_BCAST31 0x143

template <int CTRL>
__device__ __forceinline__ float dpp0_f32(float v) {
    // invalid-source lanes read 0 (bound_ctrl) — neutral for sum
    return __builtin_bit_cast(float, __builtin_amdgcn_update_dpp(
        0, __builtin_bit_cast(int, v), CTRL, 0xF, 0xF, true));
}

template <int CTRL>
__device__ __forceinline__ double dpp0_f64(double v) {
    union { double d; unsigned long long u; } x; x.d = v;
    int lo = (int)(unsigned int)(x.u & 0xffffffffull);
    int hi = (int)(unsigned int)(x.u >> 32);
    int olo = __builtin_amdgcn_update_dpp(0, lo, CTRL, 0xF, 0xF, true);
    int ohi = __builtin_amdgcn_update_dpp(0, hi, CTRL, 0xF, 0xF, true);
    union { unsigned long long u; double d; } y;
    y.u = ((unsigned long long)(unsigned int)ohi << 32) | (unsigned int)olo;
    return y.d;
}

__device__ __forceinline__ float wave_sum_f32(float v) {
    v += dpp0_f32<ROW_SHR1>(v);
    v += dpp0_f32<ROW_SHR2>(v);
    v += dpp0_f32<ROW_SHR4>(v);
    v += dpp0_f32<ROW_SHR8>(v);
    v += dpp0_f32<ROW_BCAST15>(v);
    v += dpp0_f32<ROW_BCAST31>(v);
    return v;                       // lane 63 holds the full wave sum
}

__device__ __forceinline__ double wave_sum_f64(double v) {
    v += dpp0_f64<ROW_SHR1>(v);
    v += dpp0_f64<ROW_SHR2>(v);
    v += dpp0_f64<ROW_SHR4>(v);
    v += dpp0_f64<ROW_SHR8>(v);
    v += dpp0_f64<ROW_BCAST15>(v);
    v += dpp0_f64<ROW_BCAST31>(v);
    return v;                       // lane 63 holds the full wave sum
}

__device__ __forceinline__ bool vi_gt(float v0, int i0, float v1, int i1) {
    // lexicographic (value desc, index asc) — matches jax.lax.top_k + stable sort
    return (v0 > v1) || (v0 == v1 && i0 < i1);
}

// one DPP scan step of the top-2 merge: pull partner's (v1,i1,v2,i2) via DPP
// (invalid lanes see (-inf, INT_MAX) — neutral), merge into local top-2.
template <int CTRL>
__device__ __forceinline__ void t2_step(float& v1, int& i1, float& v2, int& i2) {
    const int NEGINF = 0xFF800000;       // bits of -inf
    const int BIGIDX = 0x7fffffff;
    float ov1 = __builtin_bit_cast(float, __builtin_amdgcn_update_dpp(
        NEGINF, __builtin_bit_cast(int, v1), CTRL, 0xF, 0xF, false));
    int   oi1 = __builtin_amdgcn_update_dpp(BIGIDX, i1, CTRL, 0xF, 0xF, false);
    float ov2 = __builtin_bit_cast(float, __builtin_amdgcn_update_dpp(
        NEGINF, __builtin_bit_cast(int, v2), CTRL, 0xF, 0xF, false));
    int   oi2 = __builtin_amdgcn_update_dpp(BIGIDX, i2, CTRL, 0xF, 0xF, false);
    if (vi_gt(ov1, oi1, v1, i1)) {
        float nv2; int ni2;
        if (vi_gt(v1, i1, ov2, oi2)) { nv2 = v1;  ni2 = i1; }
        else                         { nv2 = ov2; ni2 = oi2; }
        v1 = ov1; i1 = oi1; v2 = nv2; i2 = ni2;
    } else {
        if (vi_gt(ov1, oi1, v2, i2)) { v2 = ov1; i2 = oi1; }
    }
}

__global__ __launch_bounds__(256) void mlcl_kernel(
    const float* __restrict__ x,
    const float* __restrict__ first_out,
    const float* __restrict__ weights,
    const float* __restrict__ sigma,
    float* __restrict__ out,
    int B)
{
    const int lane = threadIdx.x & 63;
    const int r = (blockIdx.x << 2) + (threadIdx.x >> 6);
    if (r >= B) return;

    // ---------- top-2 of first_out[r, 0:100] via DPP scan ----------
    const float* fo = first_out + (size_t)r * C_DIM;
    float e0 = fo[lane];
    int   j1 = lane + 64;
    float e1 = (j1 < C_DIM) ? fo[j1] : -INFINITY;

    float v1, v2; int i1, i2;
    if (vi_gt(e1, j1, e0, lane)) { v1 = e1; i1 = j1;   v2 = e0; i2 = lane; }
    else                         { v1 = e0; i1 = lane; v2 = e1; i2 = j1; }

    t2_step<ROW_SHR1>(v1, i1, v2, i2);
    t2_step<ROW_SHR2>(v1, i1, v2, i2);
    t2_step<ROW_SHR4>(v1, i1, v2, i2);
    t2_step<ROW_SHR8>(v1, i1, v2, i2);
    t2_step<ROW_BCAST15>(v1, i1, v2, i2);
    t2_step<ROW_BCAST31>(v1, i1, v2, i2);
    // lane 63 holds the global top-2; broadcast via readlane (SGPR, uniform)
    const int gi1 = __builtin_amdgcn_readlane(i1, 63);
    const int gi2 = __builtin_amdgcn_readlane(i2, 63);
    const int a = min(gi1, gi2);
    const int b = max(gi1, gi2);
    const int p = b * (b - 1) / 2 + a;

    // prefetch sigma (uniform p -> scalar load), hides under the dot loop
    const float sig = sigma[p];

    // ---------- dots + norms over D=768 ----------
    const vf4* xv = (const vf4*)(x + (size_t)r * D_DIM);
    const vf4* wv = (const vf4*)(weights + (size_t)p * (2 * D_DIM));

    // hoist all 9 coalesced 16B loads before any math
    vf4 xa0 = xv[lane],       xa1 = xv[lane + 64],       xa2 = xv[lane + 128];
    vf4 w00 = wv[lane],       w01 = wv[lane + 64],       w02 = wv[lane + 128];
    vf4 w10 = wv[192 + lane], w11 = wv[192 + lane + 64], w12 = wv[192 + lane + 128];

    float  xx = 0.f;                                  // common positive scale — f32 ok
    double d0 = 0.0, d1 = 0.0, n0 = 0.0, n1 = 0.0;    // feed argmax — f64
#define ACC(xa, w0, w1)                                                       \
    xx += xa.x * xa.x + xa.y * xa.y + xa.z * xa.z + xa.w * xa.w;              \
    d0 += (double)xa.x * w0.x + (double)xa.y * w0.y                           \
        + (double)xa.z * w0.z + (double)xa.w * w0.w;                          \
    d1 += (double)xa.x * w1.x + (double)xa.y * w1.y                           \
        + (double)xa.z * w1.z + (double)xa.w * w1.w;                          \
    n0 += (double)w0.x * w0.x + (double)w0.y * w0.y                           \
        + (double)w0.z * w0.z + (double)w0.w * w0.w;                          \
    n1 += (double)w1.x * w1.x + (double)w1.y * w1.y                           \
        + (double)w1.z * w1.z + (double)w1.w * w1.w;
    ACC(xa0, w00, w10)
    ACC(xa1, w01, w11)
    ACC(xa2, w02, w12)
#undef ACC

    xx = wave_sum_f32(xx);
    d0 = wave_sum_f64(d0);
    d1 = wave_sum_f64(d1);
    n0 = wave_sum_f64(n0);
    n1 = wave_sum_f64(n1);

    // ---------- epilogue on lane 63 (holds the sums) ----------
    if (lane == 63) {
        const double s   = (double)sig;
        const double inx = s / fmax(sqrt((double)xx), EPS_N);
        const double l0  = inx * d0 / fmax(sqrt(n0), EPS_N);
        const double l1  = inx * d1 / fmax(sqrt(n1), EPS_N);
        const int sel = (l1 > l0) ? 1 : 0;   // jnp.argmax: first index wins ties
        out[r] = (float)(sel ? b : a);
        float2 lg = make_float2((float)l0, (float)l1);
        *(float2*)(out + B + 2 * (size_t)r) = lg;    // 8B-aligned: B even
    }
}

extern "C" void kernel_launch(void* const* d_in, const int* in_sizes, int n_in,
                              void* d_out, int out_size, void* d_ws, size_t ws_size,
                              hipStream_t stream) {
    const float* x         = (const float*)d_in[0];
    const float* first_out = (const float*)d_in[1];
    const float* weights   = (const float*)d_in[2];
    const float* sigma     = (const float*)d_in[3];
    float* out = (float*)d_out;

    const int B = in_sizes[0] / D_DIM;     // 65536
    hipLaunchKernelGGL(mlcl_kernel, dim3((B + 3) / 4), dim3(256), 0, stream,
                       x, first_out, weights, sigma, out, B);
}